// Round 10
// baseline (19777.763 us; speedup 1.0000x reference)
//
#include <hip/hip_runtime.h>
#include <math.h>

#define B_   256
#define H_   512
#define V_   16000
#define M_   32
#define SOS_ 1
#define EOS_ 2
#define INV_SCALE (1.0f/2048.0f)

typedef _Float16 half_t;
typedef _Float16 f16x8 __attribute__((ext_vector_type(8)));
typedef _Float16 f16x4 __attribute__((ext_vector_type(4)));
typedef float    f32x4 __attribute__((ext_vector_type(4)));

__device__ __forceinline__ void split_f32(float x, half_t& a, half_t& b) {
    a = (half_t)x;
    b = (half_t)((x - (float)a) * 2048.0f);
}

// ---------------------------------------------------------------------------
// one-time weight split: fp32 -> fp16 hi/lo planes
// ---------------------------------------------------------------------------
__global__ __launch_bounds__(256)
void split_weights_k(const float* __restrict__ src, half_t* __restrict__ hi,
                     half_t* __restrict__ lo, int n4)
{
    const int i = blockIdx.x * 256 + threadIdx.x;
    if (i >= n4) return;
    const float4 v = ((const float4*)src)[i];
    f16x4 a, b; half_t t0, t1;
    split_f32(v.x, t0, t1); a[0] = t0; b[0] = t1;
    split_f32(v.y, t0, t1); a[1] = t0; b[1] = t1;
    split_f32(v.z, t0, t1); a[2] = t0; b[2] = t1;
    split_f32(v.w, t0, t1); a[3] = t0; b[3] = t1;
    ((f16x4*)hi)[i] = a; ((f16x4*)lo)[i] = b;
}

// ---------------------------------------------------------------------------
// init: states, splits, SOS embedding, ticket counters
// ---------------------------------------------------------------------------
__global__ __launch_bounds__(256)
void init_k(const float* __restrict__ sem_f, const float* __restrict__ emb,
            float* h0, float* h1,
            half_t* h0a, half_t* h0b, half_t* h1a, half_t* h1b,
            half_t* xa, half_t* xb,
            int* inputs, int* finished, int* cnts)
{
    const int i = blockIdx.x * 256 + threadIdx.x;
    if (i < B_ * H_) {
        const float v = sem_f[i];
        h0[i] = v; h1[i] = v;
        half_t a, b; split_f32(v, a, b);
        h0a[i] = a; h0b[i] = b;
        h1a[i] = a; h1b[i] = b;
        const int j = i & (H_ - 1);
        const float xv = emb[SOS_ * H_ + j];
        half_t c, d; split_f32(xv, c, d);
        xa[i] = c; xb[i] = d;
    }
    if (i < B_) { inputs[i] = SOS_; finished[i] = 0; }
    if (i < 320) cnts[i] = 0;      // 256 gru tickets + 64 fc tickets
}

// ---------------------------------------------------------------------------
// GRU GEMM (barrier-free, direct-global A and B frags) + fused gate.
// grid 192: ct = b%48 (ct<24 -> ih part), rt = b/48 (64-row group).
// tile 64 rows x 64 cols; 4 waves 2x2; wave 32r x 32c (rf=2, cf=2).
// Last block of each rt group (per-rt ticket==47) runs the gate for its rows.
// ---------------------------------------------------------------------------
__global__ __launch_bounds__(256, 2)
void gru_fused_k(const half_t* Aia, const half_t* Aib,
                 const half_t* Aha, const half_t* Ahb,
                 const half_t* __restrict__ Wia, const half_t* __restrict__ Wib,
                 const half_t* __restrict__ Wha, const half_t* __restrict__ Whb,
                 const float* __restrict__ b_ih, const float* __restrict__ b_hh,
                 float* PRE, float* h, half_t* ha, half_t* hb,
                 const int* finished, int* cnt)
{
    const int bidx = blockIdx.x;
    const int ct = bidx % 48;
    const int rt = bidx / 48;            // 0..3
    const bool is_ih = (ct < 24);
    const int wrow0 = (is_ih ? ct : ct - 24) * 64;
    const int row0  = rt * 64;
    const float*  bias = is_ih ? b_ih : b_hh;
    const half_t* Aa = is_ih ? Aia : Aha;
    const half_t* Ab = is_ih ? Aib : Ahb;
    const half_t* W0 = is_ih ? Wia : Wha;
    const half_t* W1 = is_ih ? Wib : Whb;

    const int tid  = threadIdx.x;
    const int wv   = tid >> 6;
    const int wr   = wv >> 1, wc = wv & 1;
    const int lane = tid & 63;
    const int ll   = lane & 15, lg = lane >> 4;

    f32x4 accM[2][2] = {};
    f32x4 accC[2][2] = {};

    const size_t aoff0 = ((size_t)(row0 + 32*wr + ll) << 9) + (lg << 3);
    const size_t boff0 = ((size_t)(wrow0 + 32*wc + ll) << 9) + (lg << 3);

#pragma unroll 2
    for (int k0 = 0; k0 < H_; k0 += 32) {
        f16x8 a0[2], a1[2], b0[2], b1[2];
        a0[0] = *(const f16x8*)(Aa + aoff0 + k0);
        a0[1] = *(const f16x8*)(Aa + aoff0 + 8192 + k0);   // +16 rows * 512
        a1[0] = *(const f16x8*)(Ab + aoff0 + k0);
        a1[1] = *(const f16x8*)(Ab + aoff0 + 8192 + k0);
        b0[0] = *(const f16x8*)(W0 + boff0 + k0);
        b0[1] = *(const f16x8*)(W0 + boff0 + 8192 + k0);   // +16 cols * 512
        b1[0] = *(const f16x8*)(W1 + boff0 + k0);
        b1[1] = *(const f16x8*)(W1 + boff0 + 8192 + k0);
#pragma unroll
        for (int cf = 0; cf < 2; ++cf)
#pragma unroll
            for (int rf = 0; rf < 2; ++rf) {
                accM[rf][cf] = __builtin_amdgcn_mfma_f32_16x16x32_f16(a0[rf], b0[cf], accM[rf][cf], 0,0,0);
                accC[rf][cf] = __builtin_amdgcn_mfma_f32_16x16x32_f16(a0[rf], b1[cf], accC[rf][cf], 0,0,0);
                accC[rf][cf] = __builtin_amdgcn_mfma_f32_16x16x32_f16(a1[rf], b0[cf], accC[rf][cf], 0,0,0);
            }
    }

#pragma unroll
    for (int cf = 0; cf < 2; ++cf) {
        const int cl = 32*wc + 16*cf + ll;          // 0..63
        const float bv = bias[wrow0 + cl];
        const int c = ct * 64 + cl;                 // 0..3071
#pragma unroll
        for (int rf = 0; rf < 2; ++rf)
#pragma unroll
            for (int r = 0; r < 4; ++r) {
                const int row = row0 + 32*wr + 16*rf + lg*4 + r;
                PRE[(size_t)row * 3072 + c] = accM[rf][cf][r] + accC[rf][cf][r] * INV_SCALE + bv;
            }
    }

    // ---- per-row-group ticket: last of the 48 ct-blocks runs the gate
    __threadfence();
    __syncthreads();
    __shared__ int isLast;
    if (tid == 0) isLast = (atomicAdd(cnt + rt, 1) == 47) ? 1 : 0;
    __syncthreads();
    if (!isLast) return;
    __threadfence();

    for (int i = tid; i < 64 * H_; i += 256) {
        const int b = row0 + (i >> 9);
        const int j = i & 511;
        if (finished[b]) continue;
        const float* pr = PRE + (size_t)b * 3072;
        const float ir = pr[j],        iz = pr[512 + j],  in_ = pr[1024 + j];
        const float hr = pr[1536 + j], hz = pr[2048 + j], hn  = pr[2560 + j];
        const float rg = 1.0f / (1.0f + expf(-(ir + hr)));
        const float zg = 1.0f / (1.0f + expf(-(iz + hz)));
        const float ng = tanhf(in_ + rg * hn);
        const int idx = b * H_ + j;
        const float hv = (1.0f - zg) * ng + zg * h[idx];
        h[idx] = hv;
        half_t a, bb; split_f32(hv, a, bb);
        ha[idx] = a; hb[idx] = bb;
    }
}

// ---------------------------------------------------------------------------
// FC GEMM (ping-pong LDS, reg prefetch) + logits + argmax partials + fused
// finalize. grid 512 (12 idle): XCD-paired mapping so the two rt tiles of a
// ct share an XCD L2. tile 128 rows x 64 cols; wave 64r x 32c (rf=4, cf=2).
// Last block of each rt group (per-rtl ticket==249) finalizes its 128 rows.
// ---------------------------------------------------------------------------
__global__ __launch_bounds__(256, 2)
void fc_fused_k(const half_t* __restrict__ Aa, const half_t* __restrict__ Ab,
                const half_t* __restrict__ W0, const half_t* __restrict__ W1,
                const float* __restrict__ fcb, const float* __restrict__ emb,
                int* finished, int* inputs,
                float* __restrict__ logits, float* pmax, int* pidx,
                float* decoded, float* masko,
                half_t* xa, half_t* xb,
                int* cnt, int t)
{
    const int bb_ = blockIdx.x;
    const int oct = bb_ & 7, seg = bb_ >> 4, rtl = (bb_ >> 3) & 1;
    const int ct = seg * 8 + oct;
    if (ct >= 250) return;                   // 12 pad blocks idle
    const int col0 = ct * 64;
    const int row0 = rtl * 128;

    __shared__ half_t Ws[2][2][64][40];      // [buf][plane][col][k] 20 KB
    __shared__ float  pmS[128][2];
    __shared__ int    piS[128][2];
    __shared__ int    isLast;
    __shared__ int    s_tok[128];

    const int tid  = threadIdx.x;
    const int wv   = tid >> 6;
    const int wr   = wv >> 1, wc = wv & 1;
    const int lane = tid & 63;
    const int ll   = lane & 15, lg = lane >> 4;
    const int sc   = tid >> 2;               // 0..63 staged col
    const int sk   = (tid & 3) * 8;          // 0,8,16,24
    const half_t* wp0 = W0 + (size_t)(col0 + sc) * H_ + sk;
    const half_t* wp1 = W1 + (size_t)(col0 + sc) * H_ + sk;

    f32x4 accM[4][2] = {};
    f32x4 accC[4][2] = {};

    // prologue: stage k-slice 0
    {
        const f16x8 c0 = *(const f16x8*)(wp0);
        const f16x8 c1 = *(const f16x8*)(wp1);
        *(f16x8*)&Ws[0][0][sc][sk] = c0;
        *(f16x8*)&Ws[0][1][sc][sk] = c1;
    }
    __syncthreads();

    const size_t aBase = ((size_t)(row0 + 64*wr + ll) << 9) + (lg << 3);

    for (int it = 0; it < 16; ++it) {
        const int cur = it & 1;
        const int k0  = it * 32;
        f16x8 nw0, nw1;
        if (it < 15) {                        // prefetch next slice into regs
            nw0 = *(const f16x8*)(wp0 + k0 + 32);
            nw1 = *(const f16x8*)(wp1 + k0 + 32);
        }
        f16x8 a0[4], a1[4];
#pragma unroll
        for (int rf = 0; rf < 4; ++rf) {
            a0[rf] = *(const f16x8*)(Aa + aBase + rf * 8192 + k0);
            a1[rf] = *(const f16x8*)(Ab + aBase + rf * 8192 + k0);
        }
#pragma unroll
        for (int cf = 0; cf < 2; ++cf) {
            const int c = 32*wc + 16*cf + ll;
            const f16x8 b0 = *(const f16x8*)&Ws[cur][0][c][lg << 3];
            const f16x8 b1 = *(const f16x8*)&Ws[cur][1][c][lg << 3];
#pragma unroll
            for (int rf = 0; rf < 4; ++rf) {
                accM[rf][cf] = __builtin_amdgcn_mfma_f32_16x16x32_f16(a0[rf], b0, accM[rf][cf], 0,0,0);
                accC[rf][cf] = __builtin_amdgcn_mfma_f32_16x16x32_f16(a0[rf], b1, accC[rf][cf], 0,0,0);
                accC[rf][cf] = __builtin_amdgcn_mfma_f32_16x16x32_f16(a1[rf], b0, accC[rf][cf], 0,0,0);
            }
        }
        if (it < 15) {
            *(f16x8*)&Ws[cur ^ 1][0][sc][sk] = nw0;
            *(f16x8*)&Ws[cur ^ 1][1][sc][sk] = nw1;
        }
        __syncthreads();
    }

    // ---- epilogue: bias, logits store, per-row argmax partials
    int fin[4][4];
    float bvv[4][4];
    int   bii[4][4];
#pragma unroll
    for (int rf = 0; rf < 4; ++rf)
#pragma unroll
        for (int r = 0; r < 4; ++r) {
            fin[rf][r] = finished[row0 + 64*wr + 16*rf + lg*4 + r];
            bvv[rf][r] = -INFINITY; bii[rf][r] = 0x7fffffff;
        }

#pragma unroll
    for (int cf = 0; cf < 2; ++cf) {
        const int col = col0 + 32*wc + 16*cf + ll;
        const float bv = fcb[col];
#pragma unroll
        for (int rf = 0; rf < 4; ++rf)
#pragma unroll
            for (int r = 0; r < 4; ++r) {
                const int row = row0 + 64*wr + 16*rf + lg*4 + r;
                const float raw = accM[rf][cf][r] + accC[rf][cf][r] * INV_SCALE + bv;
                logits[((size_t)row * M_ + t) * V_ + col] = fin[rf][r] ? 0.0f : raw;
                if (raw > bvv[rf][r]) { bvv[rf][r] = raw; bii[rf][r] = col; }  // cf asc
            }
    }

#pragma unroll
    for (int rf = 0; rf < 4; ++rf)
#pragma unroll
        for (int r = 0; r < 4; ++r) {
            float v = bvv[rf][r]; int ix = bii[rf][r];
#pragma unroll
            for (int m = 1; m < 16; m <<= 1) {
                const float ov = __shfl_xor(v, m);
                const int   oi = __shfl_xor(ix, m);
                if (ov > v || (ov == v && oi < ix)) { v = ov; ix = oi; }
            }
            if (ll == 0) {
                const int lr = 64*wr + 16*rf + lg*4 + r;    // 0..127
                pmS[lr][wc] = v; piS[lr][wc] = ix;
            }
        }
    __syncthreads();
    if (tid < 128) {
        float v = pmS[tid][0]; int ix = piS[tid][0];
        const float v2 = pmS[tid][1]; const int i2 = piS[tid][1];
        if (v2 > v || (v2 == v && i2 < ix)) { v = v2; ix = i2; }
        pmax[(size_t)(row0 + tid) * 256 + ct] = v;
        pidx[(size_t)(row0 + tid) * 256 + ct] = ix;
    }

    // ---- per-row-group ticket: last of 250 ct-blocks finalizes
    __threadfence();
    __syncthreads();
    if (tid == 0) isLast = (atomicAdd(cnt + rtl, 1) == 249) ? 1 : 0;
    __syncthreads();
    if (!isLast) return;
    __threadfence();

    // reduce 250 partials per row (one wave per row, 4 rows in flight)
    for (int rr = wv; rr < 128; rr += 4) {
        const int brow = row0 + rr;
        float v = -INFINITY; int ix = 0x7fffffff;
        for (int s = lane; s < 250; s += 64) {
            const float v2 = pmax[(size_t)brow * 256 + s];
            const int   i2 = pidx[(size_t)brow * 256 + s];
            if (v2 > v || (v2 == v && i2 < ix)) { v = v2; ix = i2; }
        }
#pragma unroll
        for (int m = 1; m < 64; m <<= 1) {
            const float ov = __shfl_xor(v, m);
            const int   oi = __shfl_xor(ix, m);
            if (ov > v || (ov == v && oi < ix)) { v = ov; ix = oi; }
        }
        if (lane == 0) {
            const int fin2 = finished[brow];
            decoded[brow * M_ + t] = fin2 ? -1.0f : (float)ix;
            masko  [brow * M_ + t] = fin2 ? 0.0f : 1.0f;
            int tok;
            if (!fin2) { inputs[brow] = ix; if (ix == EOS_) finished[brow] = 1; tok = ix; }
            else tok = inputs[brow];
            s_tok[rr] = tok;
        }
    }
    __syncthreads();
    // gather + split next-step x for this group's 128 rows
    for (int i = tid; i < 128 * H_; i += 256) {
        const int rr = i >> 9, j = i & 511;
        const float v = emb[(size_t)s_tok[rr] * H_ + j];
        half_t a, bb2; split_f32(v, a, bb2);
        xa[(size_t)(row0 + rr) * H_ + j] = a;
        xb[(size_t)(row0 + rr) * H_ + j] = bb2;
    }
}

// ---------------------------------------------------------------------------
extern "C" void kernel_launch(void* const* d_in, const int* in_sizes, int n_in,
                              void* d_out, int out_size, void* d_ws, size_t ws_size,
                              hipStream_t stream)
{
    const float* sem_f = (const float*)d_in[0];
    const float* emb   = (const float*)d_in[1];
    const float* W_ih0 = (const float*)d_in[2];
    const float* W_hh0 = (const float*)d_in[3];
    const float* b_ih0 = (const float*)d_in[4];
    const float* b_hh0 = (const float*)d_in[5];
    const float* W_ih1 = (const float*)d_in[6];
    const float* W_hh1 = (const float*)d_in[7];
    const float* b_ih1 = (const float*)d_in[8];
    const float* b_hh1 = (const float*)d_in[9];
    const float* fc_W  = (const float*)d_in[10];
    const float* fc_b  = (const float*)d_in[11];

    float* out = (float*)d_out;
    float* decoded = out;
    float* logits  = out + (size_t)B_ * M_;
    float* masko   = out + (size_t)B_ * M_ + (size_t)B_ * M_ * V_;

    float* ws = (float*)d_ws;
    float*  PRE  = ws;                            // 786432
    float*  h0   = ws + 786432;                   // 131072
    float*  h1   = ws + 917504;                   // 131072
    half_t* h0a  = (half_t*)(ws + 1048576);       // 65536 f each
    half_t* h0b  = (half_t*)(ws + 1114112);
    half_t* h1a  = (half_t*)(ws + 1179648);
    half_t* h1b  = (half_t*)(ws + 1245184);
    half_t* xa   = (half_t*)(ws + 1310720);
    half_t* xb   = (half_t*)(ws + 1376256);
    float*  pmax = ws + 1441792;                  // 256*256
    int*    pidx = (int*)(ws + 1507328);          // 256*256
    int*    inputs   = (int*)(ws + 1572864);
    int*    finished = (int*)(ws + 1573120);
    half_t* wi0a = (half_t*)(ws + 1573376);       // each GRU plane 393216 f
    half_t* wi0b = (half_t*)(ws + 1966592);
    half_t* wh0a = (half_t*)(ws + 2359808);
    half_t* wh0b = (half_t*)(ws + 2753024);
    half_t* wi1a = (half_t*)(ws + 3146240);
    half_t* wi1b = (half_t*)(ws + 3539456);
    half_t* wh1a = (half_t*)(ws + 3932672);
    half_t* wh1b = (half_t*)(ws + 4325888);
    half_t* fca  = (half_t*)(ws + 4719104);       // 4096000 f each
    half_t* fcbp = (half_t*)(ws + 8815104);
    int*    cnts = (int*)(ws + 12911104);         // 320 ints
    // total ~51.7 MB

    const int nGru4 = (1536 * 512) / 4;
    const int nFc4  = (V_ * H_) / 4;
    split_weights_k<<<(nGru4 + 255) / 256, 256, 0, stream>>>(W_ih0, wi0a, wi0b, nGru4);
    split_weights_k<<<(nGru4 + 255) / 256, 256, 0, stream>>>(W_hh0, wh0a, wh0b, nGru4);
    split_weights_k<<<(nGru4 + 255) / 256, 256, 0, stream>>>(W_ih1, wi1a, wi1b, nGru4);
    split_weights_k<<<(nGru4 + 255) / 256, 256, 0, stream>>>(W_hh1, wh1a, wh1b, nGru4);
    split_weights_k<<<(nFc4 + 255) / 256, 256, 0, stream>>>(fc_W, fca, fcbp, nFc4);
    init_k<<<(B_ * H_ + 255) / 256, 256, 0, stream>>>(
        sem_f, emb, h0, h1, h0a, h0b, h1a, h1b, xa, xb, inputs, finished, cnts);

    for (int t = 0; t < M_; ++t) {
        gru_fused_k<<<192, 256, 0, stream>>>(
            xa, xb, h0a, h0b, wi0a, wi0b, wh0a, wh0b, b_ih0, b_hh0,
            PRE, h0, h0a, h0b, finished, cnts + (t * 2 + 0) * 4);
        gru_fused_k<<<192, 256, 0, stream>>>(
            h0a, h0b, h1a, h1b, wi1a, wi1b, wh1a, wh1b, b_ih1, b_hh1,
            PRE, h1, h1a, h1b, finished, cnts + (t * 2 + 1) * 4);
        fc_fused_k<<<512, 256, 0, stream>>>(
            h1a, h1b, fca, fcbp, fc_b, emb, finished, inputs,
            logits, pmax, pidx, decoded, masko, xa, xb,
            cnts + 256 + t * 2, t);
    }
}

// Round 11
// 8404.550 us; speedup vs baseline: 2.3532x; 2.3532x over previous
//
#include <hip/hip_runtime.h>
#include <math.h>

#define B_   256
#define H_   512
#define V_   16000
#define M_   32
#define SOS_ 1
#define EOS_ 2
#define INV_SCALE (1.0f/2048.0f)

typedef _Float16 half_t;
typedef _Float16 f16x8 __attribute__((ext_vector_type(8)));
typedef _Float16 f16x4 __attribute__((ext_vector_type(4)));
typedef float    f32x4 __attribute__((ext_vector_type(4)));

__device__ __forceinline__ void split_f32(float x, half_t& a, half_t& b) {
    a = (half_t)x;
    b = (half_t)((x - (float)a) * 2048.0f);
}

// ---------------------------------------------------------------------------
// one-time weight split: fp32 -> fp16 hi/lo planes
// ---------------------------------------------------------------------------
__global__ __launch_bounds__(256)
void split_weights_k(const float* __restrict__ src, half_t* __restrict__ hi,
                     half_t* __restrict__ lo, int n4)
{
    const int i = blockIdx.x * 256 + threadIdx.x;
    if (i >= n4) return;
    const float4 v = ((const float4*)src)[i];
    f16x4 a, b; half_t t0, t1;
    split_f32(v.x, t0, t1); a[0] = t0; b[0] = t1;
    split_f32(v.y, t0, t1); a[1] = t0; b[1] = t1;
    split_f32(v.z, t0, t1); a[2] = t0; b[2] = t1;
    split_f32(v.w, t0, t1); a[3] = t0; b[3] = t1;
    ((f16x4*)hi)[i] = a; ((f16x4*)lo)[i] = b;
}

// ---------------------------------------------------------------------------
// init: h0f parity-1 plane, h1f, and the four h split planes = sem_f
// ---------------------------------------------------------------------------
__global__ __launch_bounds__(256)
void init2_k(const float* __restrict__ sem_f, float* h0f, float* h1f,
             half_t* h0a, half_t* h0b, half_t* h1a, half_t* h1b)
{
    const int i = blockIdx.x * 256 + threadIdx.x;   // grid covers B_*H_
    const float v = sem_f[i];
    h0f[B_ * H_ + i] = v;      // parity 1 (read by gru1 at t=0)
    h1f[i] = v;
    half_t a, b; split_f32(v, a, b);
    h0a[i] = a; h0b[i] = b;
    h1a[i] = a; h1b[i] = b;
}

// ---------------------------------------------------------------------------
// gru0: [prologue for ih blocks: finalize step t-1 (argmax over fc partials,
// decoded/mask writes by ct==0, inputs/finished parity update) + emb gather
// into xa/xb (self-read)] then barrier-free 64x64 GEMM -> PRE0.
// grid 192: ct=b%48 (ct<24 ih: A=x, else hh: A=h0-split old), rt=b/48.
// ---------------------------------------------------------------------------
__global__ __launch_bounds__(256, 2)
void gru0_k(half_t* xa, half_t* xb,
            const half_t* __restrict__ h0a, const half_t* __restrict__ h0b,
            const half_t* __restrict__ Wia, const half_t* __restrict__ Wib,
            const half_t* __restrict__ Wha, const half_t* __restrict__ Whb,
            const float* __restrict__ b_ih, const float* __restrict__ b_hh,
            float* __restrict__ PRE0,
            const float* __restrict__ emb,
            const float* __restrict__ pmax, const int* __restrict__ pidx,
            int* inputsBuf, int* finishedBuf,
            float* decoded, float* masko, int t)
{
    const int bidx = blockIdx.x;
    const int ct = bidx % 48;
    const int rt = bidx / 48;            // 0..3
    const bool is_ih = (ct < 24);
    const int wrow0 = (is_ih ? ct : ct - 24) * 64;
    const int row0  = rt * 64;
    const int tid  = threadIdx.x;
    const int wv   = tid >> 6;
    const int wr   = wv >> 1, wc = wv & 1;
    const int lane = tid & 63;
    const int ll   = lane & 15, lg = lane >> 4;

    __shared__ int s_tok[64];

    if (is_ih) {
        const int p = t & 1, q = p ^ 1;
        if (t == 0) {
            if (tid < 64) {
                s_tok[tid] = SOS_;
                if (ct == 0) {
                    inputsBuf[row0 + tid] = SOS_;      // parity 0
                    finishedBuf[row0 + tid] = 0;
                }
            }
        } else {
            for (int rr = wv; rr < 64; rr += 4) {       // one wave per row
                const int brow = row0 + rr;
                float v = -INFINITY; int ix = 0x7fffffff;
                for (int s = lane; s < 250; s += 64) {
                    const float v2 = pmax[(size_t)brow * 256 + s];
                    const int   i2 = pidx[(size_t)brow * 256 + s];
                    if (v2 > v || (v2 == v && i2 < ix)) { v = v2; ix = i2; }
                }
#pragma unroll
                for (int m = 1; m < 64; m <<= 1) {
                    const float ov = __shfl_xor(v, m);
                    const int   oi = __shfl_xor(ix, m);
                    if (ov > v || (ov == v && oi < ix)) { v = ov; ix = oi; }
                }
                if (lane == 0) {
                    const int finOld = finishedBuf[q * 256 + brow];
                    const int inpOld = inputsBuf[q * 256 + brow];
                    const int dec = ix;
                    const int tok = finOld ? inpOld : dec;
                    s_tok[rr] = tok;
                    if (ct == 0) {
                        decoded[brow * M_ + (t - 1)] = finOld ? -1.0f : (float)dec;
                        masko  [brow * M_ + (t - 1)] = finOld ? 0.0f : 1.0f;
                        inputsBuf[p * 256 + brow] = tok;
                        finishedBuf[p * 256 + brow] = finOld ? 1 : (dec == EOS_ ? 1 : 0);
                    }
                }
            }
        }
        __syncthreads();
        // gather + split x for this row group (self-read in GEMM below;
        // redundant identical writes by other ih blocks are benign)
        for (int i = tid; i < 64 * H_; i += 256) {
            const int rr = i >> 9, j = i & 511;
            const float v = emb[(size_t)s_tok[rr] * H_ + j];
            half_t a, b; split_f32(v, a, b);
            xa[(size_t)(row0 + rr) * H_ + j] = a;
            xb[(size_t)(row0 + rr) * H_ + j] = b;
        }
        __syncthreads();
    }

    // ---- barrier-free GEMM (round-10 body) ----
    const half_t* Aa = is_ih ? xa : h0a;
    const half_t* Ab = is_ih ? xb : h0b;
    const half_t* W0 = is_ih ? Wia : Wha;
    const half_t* W1 = is_ih ? Wib : Whb;
    const float* bias = is_ih ? b_ih : b_hh;

    f32x4 accM[2][2] = {};
    f32x4 accC[2][2] = {};
    const size_t aoff0 = ((size_t)(row0 + 32*wr + ll) << 9) + (lg << 3);
    const size_t boff0 = ((size_t)(wrow0 + 32*wc + ll) << 9) + (lg << 3);

#pragma unroll 2
    for (int k0 = 0; k0 < H_; k0 += 32) {
        f16x8 a0[2], a1[2], b0[2], b1[2];
        a0[0] = *(const f16x8*)(Aa + aoff0 + k0);
        a0[1] = *(const f16x8*)(Aa + aoff0 + 8192 + k0);
        a1[0] = *(const f16x8*)(Ab + aoff0 + k0);
        a1[1] = *(const f16x8*)(Ab + aoff0 + 8192 + k0);
        b0[0] = *(const f16x8*)(W0 + boff0 + k0);
        b0[1] = *(const f16x8*)(W0 + boff0 + 8192 + k0);
        b1[0] = *(const f16x8*)(W1 + boff0 + k0);
        b1[1] = *(const f16x8*)(W1 + boff0 + 8192 + k0);
#pragma unroll
        for (int cf = 0; cf < 2; ++cf)
#pragma unroll
            for (int rf = 0; rf < 2; ++rf) {
                accM[rf][cf] = __builtin_amdgcn_mfma_f32_16x16x32_f16(a0[rf], b0[cf], accM[rf][cf], 0,0,0);
                accC[rf][cf] = __builtin_amdgcn_mfma_f32_16x16x32_f16(a0[rf], b1[cf], accC[rf][cf], 0,0,0);
                accC[rf][cf] = __builtin_amdgcn_mfma_f32_16x16x32_f16(a1[rf], b0[cf], accC[rf][cf], 0,0,0);
            }
    }

#pragma unroll
    for (int cf = 0; cf < 2; ++cf) {
        const int cl = 32*wc + 16*cf + ll;
        const float bv = bias[wrow0 + cl];
        const int c = ct * 64 + cl;
#pragma unroll
        for (int rf = 0; rf < 2; ++rf)
#pragma unroll
            for (int r = 0; r < 4; ++r) {
                const int row = row0 + 32*wr + 16*rf + lg*4 + r;
                PRE0[(size_t)row * 3072 + c] = accM[rf][cf][r] + accC[rf][cf][r] * INV_SCALE + bv;
            }
    }
}

// ---------------------------------------------------------------------------
// gru1: [prologue for ih blocks: gate0 for own 64 rows from PRE0, h0f parity
// double-buffer, write h0 splits (self-read)] then barrier-free GEMM -> PRE1.
// hh blocks: A = h1 splits (state t-1, stable).
// ---------------------------------------------------------------------------
__global__ __launch_bounds__(256, 2)
void gru1_k(half_t* h0a, half_t* h0b,
            const half_t* __restrict__ h1a, const half_t* __restrict__ h1b,
            const half_t* __restrict__ Wia, const half_t* __restrict__ Wib,
            const half_t* __restrict__ Wha, const half_t* __restrict__ Whb,
            const float* __restrict__ b_ih, const float* __restrict__ b_hh,
            const float* __restrict__ PRE0, float* __restrict__ PRE1,
            float* h0f, const int* __restrict__ finishedBuf, int t)
{
    const int bidx = blockIdx.x;
    const int ct = bidx % 48;
    const int rt = bidx / 48;
    const bool is_ih = (ct < 24);
    const int wrow0 = (is_ih ? ct : ct - 24) * 64;
    const int row0  = rt * 64;
    const int tid  = threadIdx.x;
    const int wv   = tid >> 6;
    const int wr   = wv >> 1, wc = wv & 1;
    const int lane = tid & 63;
    const int ll   = lane & 15, lg = lane >> 4;

    if (is_ih) {
        const int p = t & 1, q = p ^ 1;
        float*       h0n = h0f + (size_t)p * (B_ * H_);
        const float* h0o = h0f + (size_t)q * (B_ * H_);
        for (int i = tid; i < 64 * H_; i += 256) {
            const int rr = i >> 9, j = i & 511;
            const int b = row0 + rr;
            const int idx = b * H_ + j;
            if (finishedBuf[p * 256 + b]) { h0n[idx] = h0o[idx]; continue; }
            const float* pr = PRE0 + (size_t)b * 3072;
            const float ir = pr[j],        iz = pr[512 + j],  in_ = pr[1024 + j];
            const float hr = pr[1536 + j], hz = pr[2048 + j], hn  = pr[2560 + j];
            const float rg = 1.0f / (1.0f + expf(-(ir + hr)));
            const float zg = 1.0f / (1.0f + expf(-(iz + hz)));
            const float ng = tanhf(in_ + rg * hn);
            const float hv = (1.0f - zg) * ng + zg * h0o[idx];
            h0n[idx] = hv;
            half_t a, bb; split_f32(hv, a, bb);
            h0a[idx] = a; h0b[idx] = bb;
        }
        __syncthreads();
    }

    const half_t* Aa = is_ih ? h0a : h1a;
    const half_t* Ab = is_ih ? h0b : h1b;
    const half_t* W0 = is_ih ? Wia : Wha;
    const half_t* W1 = is_ih ? Wib : Whb;
    const float* bias = is_ih ? b_ih : b_hh;

    f32x4 accM[2][2] = {};
    f32x4 accC[2][2] = {};
    const size_t aoff0 = ((size_t)(row0 + 32*wr + ll) << 9) + (lg << 3);
    const size_t boff0 = ((size_t)(wrow0 + 32*wc + ll) << 9) + (lg << 3);

#pragma unroll 2
    for (int k0 = 0; k0 < H_; k0 += 32) {
        f16x8 a0[2], a1[2], b0[2], b1[2];
        a0[0] = *(const f16x8*)(Aa + aoff0 + k0);
        a0[1] = *(const f16x8*)(Aa + aoff0 + 8192 + k0);
        a1[0] = *(const f16x8*)(Ab + aoff0 + k0);
        a1[1] = *(const f16x8*)(Ab + aoff0 + 8192 + k0);
        b0[0] = *(const f16x8*)(W0 + boff0 + k0);
        b0[1] = *(const f16x8*)(W0 + boff0 + 8192 + k0);
        b1[0] = *(const f16x8*)(W1 + boff0 + k0);
        b1[1] = *(const f16x8*)(W1 + boff0 + 8192 + k0);
#pragma unroll
        for (int cf = 0; cf < 2; ++cf)
#pragma unroll
            for (int rf = 0; rf < 2; ++rf) {
                accM[rf][cf] = __builtin_amdgcn_mfma_f32_16x16x32_f16(a0[rf], b0[cf], accM[rf][cf], 0,0,0);
                accC[rf][cf] = __builtin_amdgcn_mfma_f32_16x16x32_f16(a0[rf], b1[cf], accC[rf][cf], 0,0,0);
                accC[rf][cf] = __builtin_amdgcn_mfma_f32_16x16x32_f16(a1[rf], b0[cf], accC[rf][cf], 0,0,0);
            }
    }

#pragma unroll
    for (int cf = 0; cf < 2; ++cf) {
        const int cl = 32*wc + 16*cf + ll;
        const float bv = bias[wrow0 + cl];
        const int c = ct * 64 + cl;
#pragma unroll
        for (int rf = 0; rf < 2; ++rf)
#pragma unroll
            for (int r = 0; r < 4; ++r) {
                const int row = row0 + 32*wr + 16*rf + lg*4 + r;
                PRE1[(size_t)row * 3072 + c] = accM[rf][cf][r] + accC[rf][cf][r] * INV_SCALE + bv;
            }
    }
}

// ---------------------------------------------------------------------------
// gate1: element-local (1 elem/thread), single-buffer h1f is safe.
// ---------------------------------------------------------------------------
__global__ __launch_bounds__(256)
void gate1_k(const float* __restrict__ PRE1, float* h1f,
             half_t* h1a, half_t* h1b,
             const int* __restrict__ finishedBuf, int t)
{
    const int idx = blockIdx.x * 256 + threadIdx.x;
    const int b = idx >> 9;
    const int j = idx & 511;
    if (finishedBuf[(t & 1) * 256 + b]) return;
    const float* pr = PRE1 + (size_t)b * 3072;
    const float ir = pr[j],        iz = pr[512 + j],  in_ = pr[1024 + j];
    const float hr = pr[1536 + j], hz = pr[2048 + j], hn  = pr[2560 + j];
    const float rg = 1.0f / (1.0f + expf(-(ir + hr)));
    const float zg = 1.0f / (1.0f + expf(-(iz + hz)));
    const float ng = tanhf(in_ + rg * hn);
    const float hv = (1.0f - zg) * ng + zg * h1f[idx];
    h1f[idx] = hv;
    half_t a, bb; split_f32(hv, a, bb);
    h1a[idx] = a; h1b[idx] = bb;
}

// ---------------------------------------------------------------------------
// fc: ping-pong LDS GEMM (round-10 body) + logits + argmax partials.
// grid (250, 2): 64-col x 128-row tiles.
// ---------------------------------------------------------------------------
__global__ __launch_bounds__(256, 2)
void fc_k(const half_t* __restrict__ Aa, const half_t* __restrict__ Ab,
          const half_t* __restrict__ W0, const half_t* __restrict__ W1,
          const float* __restrict__ fcb, const int* __restrict__ finishedBuf,
          float* __restrict__ logits, float* pmax, int* pidx, int t)
{
    const int ct  = blockIdx.x;          // 0..249
    const int rtl = blockIdx.y;          // 0..1
    const int col0 = ct * 64;
    const int row0 = rtl * 128;

    __shared__ half_t Ws[2][2][64][40];
    __shared__ float  pmS[128][2];
    __shared__ int    piS[128][2];

    const int tid  = threadIdx.x;
    const int wv   = tid >> 6;
    const int wr   = wv >> 1, wc = wv & 1;
    const int lane = tid & 63;
    const int ll   = lane & 15, lg = lane >> 4;
    const int sc   = tid >> 2;
    const int sk   = (tid & 3) * 8;
    const half_t* wp0 = W0 + (size_t)(col0 + sc) * H_ + sk;
    const half_t* wp1 = W1 + (size_t)(col0 + sc) * H_ + sk;

    f32x4 accM[4][2] = {};
    f32x4 accC[4][2] = {};

    {
        const f16x8 c0 = *(const f16x8*)(wp0);
        const f16x8 c1 = *(const f16x8*)(wp1);
        *(f16x8*)&Ws[0][0][sc][sk] = c0;
        *(f16x8*)&Ws[0][1][sc][sk] = c1;
    }
    __syncthreads();

    const size_t aBase = ((size_t)(row0 + 64*wr + ll) << 9) + (lg << 3);
    const int p = t & 1;

    for (int it = 0; it < 16; ++it) {
        const int cur = it & 1;
        const int k0  = it * 32;
        f16x8 nw0, nw1;
        if (it < 15) {
            nw0 = *(const f16x8*)(wp0 + k0 + 32);
            nw1 = *(const f16x8*)(wp1 + k0 + 32);
        }
        f16x8 a0[4], a1[4];
#pragma unroll
        for (int rf = 0; rf < 4; ++rf) {
            a0[rf] = *(const f16x8*)(Aa + aBase + rf * 8192 + k0);
            a1[rf] = *(const f16x8*)(Ab + aBase + rf * 8192 + k0);
        }
#pragma unroll
        for (int cf = 0; cf < 2; ++cf) {
            const int c = 32*wc + 16*cf + ll;
            const f16x8 b0 = *(const f16x8*)&Ws[cur][0][c][lg << 3];
            const f16x8 b1 = *(const f16x8*)&Ws[cur][1][c][lg << 3];
#pragma unroll
            for (int rf = 0; rf < 4; ++rf) {
                accM[rf][cf] = __builtin_amdgcn_mfma_f32_16x16x32_f16(a0[rf], b0, accM[rf][cf], 0,0,0);
                accC[rf][cf] = __builtin_amdgcn_mfma_f32_16x16x32_f16(a0[rf], b1, accC[rf][cf], 0,0,0);
                accC[rf][cf] = __builtin_amdgcn_mfma_f32_16x16x32_f16(a1[rf], b0, accC[rf][cf], 0,0,0);
            }
        }
        if (it < 15) {
            *(f16x8*)&Ws[cur ^ 1][0][sc][sk] = nw0;
            *(f16x8*)&Ws[cur ^ 1][1][sc][sk] = nw1;
        }
        __syncthreads();
    }

    int fin[4][4];
    float bvv[4][4];
    int   bii[4][4];
#pragma unroll
    for (int rf = 0; rf < 4; ++rf)
#pragma unroll
        for (int r = 0; r < 4; ++r) {
            fin[rf][r] = finishedBuf[p * 256 + row0 + 64*wr + 16*rf + lg*4 + r];
            bvv[rf][r] = -INFINITY; bii[rf][r] = 0x7fffffff;
        }

#pragma unroll
    for (int cf = 0; cf < 2; ++cf) {
        const int col = col0 + 32*wc + 16*cf + ll;
        const float bv = fcb[col];
#pragma unroll
        for (int rf = 0; rf < 4; ++rf)
#pragma unroll
            for (int r = 0; r < 4; ++r) {
                const int row = row0 + 64*wr + 16*rf + lg*4 + r;
                const float raw = accM[rf][cf][r] + accC[rf][cf][r] * INV_SCALE + bv;
                logits[((size_t)row * M_ + t) * V_ + col] = fin[rf][r] ? 0.0f : raw;
                if (raw > bvv[rf][r]) { bvv[rf][r] = raw; bii[rf][r] = col; }
            }
    }

#pragma unroll
    for (int rf = 0; rf < 4; ++rf)
#pragma unroll
        for (int r = 0; r < 4; ++r) {
            float v = bvv[rf][r]; int ix = bii[rf][r];
#pragma unroll
            for (int m = 1; m < 16; m <<= 1) {
                const float ov = __shfl_xor(v, m);
                const int   oi = __shfl_xor(ix, m);
                if (ov > v || (ov == v && oi < ix)) { v = ov; ix = oi; }
            }
            if (ll == 0) {
                const int lr = 64*wr + 16*rf + lg*4 + r;
                pmS[lr][wc] = v; piS[lr][wc] = ix;
            }
        }
    __syncthreads();
    if (tid < 128) {
        float v = pmS[tid][0]; int ix = piS[tid][0];
        const float v2 = pmS[tid][1]; const int i2 = piS[tid][1];
        if (v2 > v || (v2 == v && i2 < ix)) { v = v2; ix = i2; }
        pmax[(size_t)(row0 + tid) * 256 + ct] = v;
        pidx[(size_t)(row0 + tid) * 256 + ct] = ix;
    }
}

// ---------------------------------------------------------------------------
// final: write decoded/mask for step M-1 from the last fc partials.
// grid 4 x 256, one wave per row.
// ---------------------------------------------------------------------------
__global__ __launch_bounds__(256)
void final_k(const float* __restrict__ pmax, const int* __restrict__ pidx,
             const int* __restrict__ finishedBuf,
             float* decoded, float* masko)
{
    const int row0 = blockIdx.x * 64;
    const int tid = threadIdx.x;
    const int wv = tid >> 6, lane = tid & 63;
    const int q = (M_ - 1) & 1;     // state parity of step 31
    for (int rr = wv; rr < 64; rr += 4) {
        const int brow = row0 + rr;
        float v = -INFINITY; int ix = 0x7fffffff;
        for (int s = lane; s < 250; s += 64) {
            const float v2 = pmax[(size_t)brow * 256 + s];
            const int   i2 = pidx[(size_t)brow * 256 + s];
            if (v2 > v || (v2 == v && i2 < ix)) { v = v2; ix = i2; }
        }
#pragma unroll
        for (int m = 1; m < 64; m <<= 1) {
            const float ov = __shfl_xor(v, m);
            const int   oi = __shfl_xor(ix, m);
            if (ov > v || (ov == v && oi < ix)) { v = ov; ix = oi; }
        }
        if (lane == 0) {
            const int finOld = finishedBuf[q * 256 + brow];
            decoded[brow * M_ + (M_ - 1)] = finOld ? -1.0f : (float)ix;
            masko  [brow * M_ + (M_ - 1)] = finOld ? 0.0f : 1.0f;
        }
    }
}

// ---------------------------------------------------------------------------
extern "C" void kernel_launch(void* const* d_in, const int* in_sizes, int n_in,
                              void* d_out, int out_size, void* d_ws, size_t ws_size,
                              hipStream_t stream)
{
    const float* sem_f = (const float*)d_in[0];
    const float* emb   = (const float*)d_in[1];
    const float* W_ih0 = (const float*)d_in[2];
    const float* W_hh0 = (const float*)d_in[3];
    const float* b_ih0 = (const float*)d_in[4];
    const float* b_hh0 = (const float*)d_in[5];
    const float* W_ih1 = (const float*)d_in[6];
    const float* W_hh1 = (const float*)d_in[7];
    const float* b_ih1 = (const float*)d_in[8];
    const float* b_hh1 = (const float*)d_in[9];
    const float* fc_W  = (const float*)d_in[10];
    const float* fc_b  = (const float*)d_in[11];

    float* out = (float*)d_out;
    float* decoded = out;
    float* logits  = out + (size_t)B_ * M_;
    float* masko   = out + (size_t)B_ * M_ + (size_t)B_ * M_ * V_;

    float* ws = (float*)d_ws;
    float*  PRE0 = ws;                            // 786432
    float*  PRE1 = ws + 786432;                   // 786432
    float*  h0f  = ws + 1572864;                  // 2 x 131072 (parity planes)
    float*  h1f  = ws + 1835008;                  // 131072
    half_t* h0a  = (half_t*)(ws + 1966080);       // 65536 f each
    half_t* h0b  = (half_t*)(ws + 2031616);
    half_t* h1a  = (half_t*)(ws + 2097152);
    half_t* h1b  = (half_t*)(ws + 2162688);
    half_t* xa   = (half_t*)(ws + 2228224);
    half_t* xb   = (half_t*)(ws + 2293760);
    float*  pmax = ws + 2359296;                  // 256*256
    int*    pidx = (int*)(ws + 2424832);          // 256*256
    int*    inputsBuf   = (int*)(ws + 2490368);   // 2 x 256
    int*    finishedBuf = (int*)(ws + 2490880);   // 2 x 256
    half_t* wi0a = (half_t*)(ws + 2491392);       // each GRU plane 393216 f
    half_t* wi0b = (half_t*)(ws + 2884608);
    half_t* wh0a = (half_t*)(ws + 3277824);
    half_t* wh0b = (half_t*)(ws + 3671040);
    half_t* wi1a = (half_t*)(ws + 4064256);
    half_t* wi1b = (half_t*)(ws + 4457472);
    half_t* wh1a = (half_t*)(ws + 4850688);
    half_t* wh1b = (half_t*)(ws + 5243904);
    half_t* fca  = (half_t*)(ws + 5637120);       // 4096000 f each
    half_t* fcbp = (half_t*)(ws + 9733120);
    // total 13,829,120 floats = 55.3 MB

    const int nGru4 = (1536 * 512) / 4;
    const int nFc4  = (V_ * H_) / 4;
    split_weights_k<<<(nGru4 + 255) / 256, 256, 0, stream>>>(W_ih0, wi0a, wi0b, nGru4);
    split_weights_k<<<(nGru4 + 255) / 256, 256, 0, stream>>>(W_hh0, wh0a, wh0b, nGru4);
    split_weights_k<<<(nGru4 + 255) / 256, 256, 0, stream>>>(W_ih1, wi1a, wi1b, nGru4);
    split_weights_k<<<(nGru4 + 255) / 256, 256, 0, stream>>>(W_hh1, wh1a, wh1b, nGru4);
    split_weights_k<<<(nFc4 + 255) / 256, 256, 0, stream>>>(fc_W, fca, fcbp, nFc4);
    init2_k<<<(B_ * H_) / 256, 256, 0, stream>>>(sem_f, h0f, h1f, h0a, h0b, h1a, h1b);

    for (int t = 0; t < M_; ++t) {
        gru0_k<<<192, 256, 0, stream>>>(
            xa, xb, h0a, h0b, wi0a, wi0b, wh0a, wh0b, b_ih0, b_hh0, PRE0,
            emb, pmax, pidx, inputsBuf, finishedBuf, decoded, masko, t);
        gru1_k<<<192, 256, 0, stream>>>(
            h0a, h0b, h1a, h1b, wi1a, wi1b, wh1a, wh1b, b_ih1, b_hh1,
            PRE0, PRE1, h0f, finishedBuf, t);
        gate1_k<<<(B_ * H_) / 256, 256, 0, stream>>>(
            PRE1, h1f, h1a, h1b, finishedBuf, t);
        fc_k<<<dim3(250, 2), 256, 0, stream>>>(
            h1a, h1b, fca, fcbp, fc_b, finishedBuf, logits, pmax, pidx, t);
    }
    final_k<<<4, 256, 0, stream>>>(pmax, pidx, finishedBuf, decoded, masko);
}

// Round 12
// 7998.524 us; speedup vs baseline: 2.4727x; 1.0508x over previous
//
#include <hip/hip_runtime.h>
#include <math.h>

#define B_   256
#define H_   512
#define V_   16000
#define M_   32
#define SOS_ 1
#define EOS_ 2
#define INV_SCALE (1.0f/2048.0f)

typedef _Float16 half_t;
typedef _Float16 f16x8 __attribute__((ext_vector_type(8)));
typedef _Float16 f16x4 __attribute__((ext_vector_type(4)));
typedef float    f32x4 __attribute__((ext_vector_type(4)));

__device__ __forceinline__ void split_f32(float x, half_t& a, half_t& b) {
    a = (half_t)x;
    b = (half_t)((x - (float)a) * 2048.0f);
}

// ---------------------------------------------------------------------------
// one-time weight split: fp32 -> fp16 hi/lo planes
// ---------------------------------------------------------------------------
__global__ __launch_bounds__(256)
void split_weights_k(const float* __restrict__ src, half_t* __restrict__ hi,
                     half_t* __restrict__ lo, int n4)
{
    const int i = blockIdx.x * 256 + threadIdx.x;
    if (i >= n4) return;
    const float4 v = ((const float4*)src)[i];
    f16x4 a, b; half_t t0, t1;
    split_f32(v.x, t0, t1); a[0] = t0; b[0] = t1;
    split_f32(v.y, t0, t1); a[1] = t0; b[1] = t1;
    split_f32(v.z, t0, t1); a[2] = t0; b[2] = t1;
    split_f32(v.w, t0, t1); a[3] = t0; b[3] = t1;
    ((f16x4*)hi)[i] = a; ((f16x4*)lo)[i] = b;
}

// ---------------------------------------------------------------------------
// init: h0f parity-1 plane, h1f, and the four h split planes = sem_f
// ---------------------------------------------------------------------------
__global__ __launch_bounds__(256)
void init2_k(const float* __restrict__ sem_f, float* h0f, float* h1f,
             half_t* h0a, half_t* h0b, half_t* h1a, half_t* h1b)
{
    const int i = blockIdx.x * 256 + threadIdx.x;   // grid covers B_*H_
    const float v = sem_f[i];
    h0f[B_ * H_ + i] = v;      // parity 1 (read by gru1 at t=0)
    h1f[i] = v;
    half_t a, b; split_f32(v, a, b);
    h0a[i] = a; h0b[i] = b;
    h1a[i] = a; h1b[i] = b;
}

// ---------------------------------------------------------------------------
// gru0: [prologue for ih blocks: finalize step t-1 (argmax over fc partials,
// decoded/mask writes by ct==0, inputs/finished parity update) + emb gather
// into xa/xb (self-read)] then barrier-free 64x64 GEMM -> PRE0.
// grid 192: ct=b%48 (ct<24 ih: A=x, else hh: A=h0-split old), rt=b/48.
// ---------------------------------------------------------------------------
__global__ __launch_bounds__(256, 2)
void gru0_k(half_t* xa, half_t* xb,
            const half_t* __restrict__ h0a, const half_t* __restrict__ h0b,
            const half_t* __restrict__ Wia, const half_t* __restrict__ Wib,
            const half_t* __restrict__ Wha, const half_t* __restrict__ Whb,
            const float* __restrict__ b_ih, const float* __restrict__ b_hh,
            float* __restrict__ PRE0,
            const float* __restrict__ emb,
            const float* __restrict__ pmax, const int* __restrict__ pidx,
            int* inputsBuf, int* finishedBuf,
            float* decoded, float* masko, int t)
{
    const int bidx = blockIdx.x;
    const int ct = bidx % 48;
    const int rt = bidx / 48;            // 0..3
    const bool is_ih = (ct < 24);
    const int wrow0 = (is_ih ? ct : ct - 24) * 64;
    const int row0  = rt * 64;
    const int tid  = threadIdx.x;
    const int wv   = tid >> 6;
    const int wr   = wv >> 1, wc = wv & 1;
    const int lane = tid & 63;
    const int ll   = lane & 15, lg = lane >> 4;

    __shared__ int s_tok[64];

    if (is_ih) {
        const int p = t & 1, q = p ^ 1;
        if (t == 0) {
            if (tid < 64) {
                s_tok[tid] = SOS_;
                if (ct == 0) {
                    inputsBuf[row0 + tid] = SOS_;      // parity 0
                    finishedBuf[row0 + tid] = 0;
                }
            }
        } else {
            for (int rr = wv; rr < 64; rr += 4) {       // one wave per row
                const int brow = row0 + rr;
                float v = -INFINITY; int ix = 0x7fffffff;
                for (int s = lane; s < 125; s += 64) {
                    const float v2 = pmax[(size_t)brow * 256 + s];
                    const int   i2 = pidx[(size_t)brow * 256 + s];
                    if (v2 > v || (v2 == v && i2 < ix)) { v = v2; ix = i2; }
                }
#pragma unroll
                for (int m = 1; m < 64; m <<= 1) {
                    const float ov = __shfl_xor(v, m);
                    const int   oi = __shfl_xor(ix, m);
                    if (ov > v || (ov == v && oi < ix)) { v = ov; ix = oi; }
                }
                if (lane == 0) {
                    const int finOld = finishedBuf[q * 256 + brow];
                    const int inpOld = inputsBuf[q * 256 + brow];
                    const int dec = ix;
                    const int tok = finOld ? inpOld : dec;
                    s_tok[rr] = tok;
                    if (ct == 0) {
                        decoded[brow * M_ + (t - 1)] = finOld ? -1.0f : (float)dec;
                        masko  [brow * M_ + (t - 1)] = finOld ? 0.0f : 1.0f;
                        inputsBuf[p * 256 + brow] = tok;
                        finishedBuf[p * 256 + brow] = finOld ? 1 : (dec == EOS_ ? 1 : 0);
                    }
                }
            }
        }
        __syncthreads();
        // gather + split x for this row group (self-read in GEMM below;
        // redundant identical writes by other ih blocks are benign)
        for (int i = tid; i < 64 * H_; i += 256) {
            const int rr = i >> 9, j = i & 511;
            const float v = emb[(size_t)s_tok[rr] * H_ + j];
            half_t a, b; split_f32(v, a, b);
            xa[(size_t)(row0 + rr) * H_ + j] = a;
            xb[(size_t)(row0 + rr) * H_ + j] = b;
        }
        __syncthreads();
    }

    // ---- barrier-free GEMM ----
    const half_t* Aa = is_ih ? xa : h0a;
    const half_t* Ab = is_ih ? xb : h0b;
    const half_t* W0 = is_ih ? Wia : Wha;
    const half_t* W1 = is_ih ? Wib : Whb;
    const float* bias = is_ih ? b_ih : b_hh;

    f32x4 accM[2][2] = {};
    f32x4 accC[2][2] = {};
    const size_t aoff0 = ((size_t)(row0 + 32*wr + ll) << 9) + (lg << 3);
    const size_t boff0 = ((size_t)(wrow0 + 32*wc + ll) << 9) + (lg << 3);

#pragma unroll 2
    for (int k0 = 0; k0 < H_; k0 += 32) {
        f16x8 a0[2], a1[2], b0[2], b1[2];
        a0[0] = *(const f16x8*)(Aa + aoff0 + k0);
        a0[1] = *(const f16x8*)(Aa + aoff0 + 8192 + k0);
        a1[0] = *(const f16x8*)(Ab + aoff0 + k0);
        a1[1] = *(const f16x8*)(Ab + aoff0 + 8192 + k0);
        b0[0] = *(const f16x8*)(W0 + boff0 + k0);
        b0[1] = *(const f16x8*)(W0 + boff0 + 8192 + k0);
        b1[0] = *(const f16x8*)(W1 + boff0 + k0);
        b1[1] = *(const f16x8*)(W1 + boff0 + 8192 + k0);
#pragma unroll
        for (int cf = 0; cf < 2; ++cf)
#pragma unroll
            for (int rf = 0; rf < 2; ++rf) {
                accM[rf][cf] = __builtin_amdgcn_mfma_f32_16x16x32_f16(a0[rf], b0[cf], accM[rf][cf], 0,0,0);
                accC[rf][cf] = __builtin_amdgcn_mfma_f32_16x16x32_f16(a0[rf], b1[cf], accC[rf][cf], 0,0,0);
                accC[rf][cf] = __builtin_amdgcn_mfma_f32_16x16x32_f16(a1[rf], b0[cf], accC[rf][cf], 0,0,0);
            }
    }

#pragma unroll
    for (int cf = 0; cf < 2; ++cf) {
        const int cl = 32*wc + 16*cf + ll;
        const float bv = bias[wrow0 + cl];
        const int c = ct * 64 + cl;
#pragma unroll
        for (int rf = 0; rf < 2; ++rf)
#pragma unroll
            for (int r = 0; r < 4; ++r) {
                const int row = row0 + 32*wr + 16*rf + lg*4 + r;
                PRE0[(size_t)row * 3072 + c] = accM[rf][cf][r] + accC[rf][cf][r] * INV_SCALE + bv;
            }
    }
}

// ---------------------------------------------------------------------------
// gru1: [prologue for ih blocks: gate0 for own 64 rows from PRE0, h0f parity
// double-buffer, write h0 splits (self-read)] then barrier-free GEMM -> PRE1.
// hh blocks: A = h1 splits (state t-1, stable).
// ---------------------------------------------------------------------------
__global__ __launch_bounds__(256, 2)
void gru1_k(half_t* h0a, half_t* h0b,
            const half_t* __restrict__ h1a, const half_t* __restrict__ h1b,
            const half_t* __restrict__ Wia, const half_t* __restrict__ Wib,
            const half_t* __restrict__ Wha, const half_t* __restrict__ Whb,
            const float* __restrict__ b_ih, const float* __restrict__ b_hh,
            const float* __restrict__ PRE0, float* __restrict__ PRE1,
            float* h0f, const int* __restrict__ finishedBuf, int t)
{
    const int bidx = blockIdx.x;
    const int ct = bidx % 48;
    const int rt = bidx / 48;
    const bool is_ih = (ct < 24);
    const int wrow0 = (is_ih ? ct : ct - 24) * 64;
    const int row0  = rt * 64;
    const int tid  = threadIdx.x;
    const int wv   = tid >> 6;
    const int wr   = wv >> 1, wc = wv & 1;
    const int lane = tid & 63;
    const int ll   = lane & 15, lg = lane >> 4;

    if (is_ih) {
        const int p = t & 1, q = p ^ 1;
        float*       h0n = h0f + (size_t)p * (B_ * H_);
        const float* h0o = h0f + (size_t)q * (B_ * H_);
        for (int i = tid; i < 64 * H_; i += 256) {
            const int rr = i >> 9, j = i & 511;
            const int b = row0 + rr;
            const int idx = b * H_ + j;
            if (finishedBuf[p * 256 + b]) { h0n[idx] = h0o[idx]; continue; }
            const float* pr = PRE0 + (size_t)b * 3072;
            const float ir = pr[j],        iz = pr[512 + j],  in_ = pr[1024 + j];
            const float hr = pr[1536 + j], hz = pr[2048 + j], hn  = pr[2560 + j];
            const float rg = 1.0f / (1.0f + expf(-(ir + hr)));
            const float zg = 1.0f / (1.0f + expf(-(iz + hz)));
            const float ng = tanhf(in_ + rg * hn);
            const float hv = (1.0f - zg) * ng + zg * h0o[idx];
            h0n[idx] = hv;
            half_t a, bb; split_f32(hv, a, bb);
            h0a[idx] = a; h0b[idx] = bb;
        }
        __syncthreads();
    }

    const half_t* Aa = is_ih ? h0a : h1a;
    const half_t* Ab = is_ih ? h0b : h1b;
    const half_t* W0 = is_ih ? Wia : Wha;
    const half_t* W1 = is_ih ? Wib : Whb;
    const float* bias = is_ih ? b_ih : b_hh;

    f32x4 accM[2][2] = {};
    f32x4 accC[2][2] = {};
    const size_t aoff0 = ((size_t)(row0 + 32*wr + ll) << 9) + (lg << 3);
    const size_t boff0 = ((size_t)(wrow0 + 32*wc + ll) << 9) + (lg << 3);

#pragma unroll 2
    for (int k0 = 0; k0 < H_; k0 += 32) {
        f16x8 a0[2], a1[2], b0[2], b1[2];
        a0[0] = *(const f16x8*)(Aa + aoff0 + k0);
        a0[1] = *(const f16x8*)(Aa + aoff0 + 8192 + k0);
        a1[0] = *(const f16x8*)(Ab + aoff0 + k0);
        a1[1] = *(const f16x8*)(Ab + aoff0 + 8192 + k0);
        b0[0] = *(const f16x8*)(W0 + boff0 + k0);
        b0[1] = *(const f16x8*)(W0 + boff0 + 8192 + k0);
        b1[0] = *(const f16x8*)(W1 + boff0 + k0);
        b1[1] = *(const f16x8*)(W1 + boff0 + 8192 + k0);
#pragma unroll
        for (int cf = 0; cf < 2; ++cf)
#pragma unroll
            for (int rf = 0; rf < 2; ++rf) {
                accM[rf][cf] = __builtin_amdgcn_mfma_f32_16x16x32_f16(a0[rf], b0[cf], accM[rf][cf], 0,0,0);
                accC[rf][cf] = __builtin_amdgcn_mfma_f32_16x16x32_f16(a0[rf], b1[cf], accC[rf][cf], 0,0,0);
                accC[rf][cf] = __builtin_amdgcn_mfma_f32_16x16x32_f16(a1[rf], b0[cf], accC[rf][cf], 0,0,0);
            }
    }

#pragma unroll
    for (int cf = 0; cf < 2; ++cf) {
        const int cl = 32*wc + 16*cf + ll;
        const float bv = bias[wrow0 + cl];
        const int c = ct * 64 + cl;
#pragma unroll
        for (int rf = 0; rf < 2; ++rf)
#pragma unroll
            for (int r = 0; r < 4; ++r) {
                const int row = row0 + 32*wr + 16*rf + lg*4 + r;
                PRE1[(size_t)row * 3072 + c] = accM[rf][cf][r] + accC[rf][cf][r] * INV_SCALE + bv;
            }
    }
}

// ---------------------------------------------------------------------------
// gate1: element-local (1 elem/thread), single-buffer h1f is safe.
// ---------------------------------------------------------------------------
__global__ __launch_bounds__(256)
void gate1_k(const float* __restrict__ PRE1, float* h1f,
             half_t* h1a, half_t* h1b,
             const int* __restrict__ finishedBuf, int t)
{
    const int idx = blockIdx.x * 256 + threadIdx.x;
    const int b = idx >> 9;
    const int j = idx & 511;
    if (finishedBuf[(t & 1) * 256 + b]) return;
    const float* pr = PRE1 + (size_t)b * 3072;
    const float ir = pr[j],        iz = pr[512 + j],  in_ = pr[1024 + j];
    const float hr = pr[1536 + j], hz = pr[2048 + j], hn  = pr[2560 + j];
    const float rg = 1.0f / (1.0f + expf(-(ir + hr)));
    const float zg = 1.0f / (1.0f + expf(-(iz + hz)));
    const float ng = tanhf(in_ + rg * hn);
    const float hv = (1.0f - zg) * ng + zg * h1f[idx];
    h1f[idx] = hv;
    half_t a, bb; split_f32(hv, a, bb);
    h1a[idx] = a; h1b[idx] = bb;
}

// ---------------------------------------------------------------------------
// fc: ROUND-3 BODY (proven spill-free). 128-col x 64-row tiles, grid (125,4).
// Waves 2x2; wave = 32 rows x 64 cols (rf=2, cf=4). LDS-staged W, 2 barriers.
// Epilogue: bias, logits (float4), argmax partials -> pmax/pidx stride 256.
// ---------------------------------------------------------------------------
__global__ __launch_bounds__(256)
void fc_gemm_mfma(const half_t* __restrict__ Aa, const half_t* __restrict__ Ab,
                  const half_t* __restrict__ W0, const half_t* __restrict__ W1,
                  const float* __restrict__ fcb,
                  const int* __restrict__ finishedBuf,
                  float* __restrict__ logits,
                  float* pmax, int* pidx, int t)
{
    const int ct = blockIdx.x;            // 0..124
    const int rt = blockIdx.y;            // 0..3
    const int col0 = ct * 128;
    const int row0 = rt * 64;
    const int p = t & 1;

    __shared__ half_t W0s[128][40];
    __shared__ half_t W1s[128][40];
    __shared__ float  pmS[64][2];
    __shared__ int    piS[64][2];

    const int tid  = threadIdx.x;
    const int wv   = tid >> 6;
    const int wr   = wv >> 1, wc = wv & 1;
    const int lane = tid & 63;
    const int ll   = lane & 15, lg = lane >> 4;

    const int sc = tid >> 1;
    const int sk = (tid & 1) * 16;
    const half_t* wp0 = W0 + (size_t)(col0 + sc) * H_ + sk;
    const half_t* wp1 = W1 + (size_t)(col0 + sc) * H_ + sk;

    f32x4 accM[2][4] = {};
    f32x4 accC[2][4] = {};

    for (int k0 = 0; k0 < H_; k0 += 32) {
        const f16x8 s0 = *(const f16x8*)(wp0 + k0);
        const f16x8 s1 = *(const f16x8*)(wp0 + k0 + 8);
        const f16x8 s2 = *(const f16x8*)(wp1 + k0);
        const f16x8 s3 = *(const f16x8*)(wp1 + k0 + 8);
        __syncthreads();
        *(f16x8*)&W0s[sc][sk]     = s0;
        *(f16x8*)&W0s[sc][sk + 8] = s1;
        *(f16x8*)&W1s[sc][sk]     = s2;
        *(f16x8*)&W1s[sc][sk + 8] = s3;
        __syncthreads();

        f16x8 a0[2], a1[2];
#pragma unroll
        for (int rf = 0; rf < 2; ++rf) {
            const size_t off = ((size_t)(row0 + 32*wr + 16*rf + ll) << 9) + k0 + (lg << 3);
            a0[rf] = *(const f16x8*)(Aa + off);
            a1[rf] = *(const f16x8*)(Ab + off);
        }
#pragma unroll
        for (int cf = 0; cf < 4; ++cf) {
            const int c = 64*wc + 16*cf + ll;
            const f16x8 b0 = *(const f16x8*)&W0s[c][lg << 3];
            const f16x8 b1 = *(const f16x8*)&W1s[c][lg << 3];
#pragma unroll
            for (int rf = 0; rf < 2; ++rf) {
                accM[rf][cf] = __builtin_amdgcn_mfma_f32_16x16x32_f16(a0[rf], b0, accM[rf][cf], 0,0,0);
                accC[rf][cf] = __builtin_amdgcn_mfma_f32_16x16x32_f16(a0[rf], b1, accC[rf][cf], 0,0,0);
                accC[rf][cf] = __builtin_amdgcn_mfma_f32_16x16x32_f16(a1[rf], b0, accC[rf][cf], 0,0,0);
            }
        }
    }

    int fin[2][4];
#pragma unroll
    for (int rf = 0; rf < 2; ++rf)
#pragma unroll
        for (int r = 0; r < 4; ++r)
            fin[rf][r] = finishedBuf[p * 256 + row0 + 32*wr + 16*rf + lg*4 + r];

    float bvv[2][4];
    int   bii[2][4];
#pragma unroll
    for (int rf = 0; rf < 2; ++rf)
#pragma unroll
        for (int r = 0; r < 4; ++r) { bvv[rf][r] = -INFINITY; bii[rf][r] = 0x7fffffff; }

#pragma unroll
    for (int cf = 0; cf < 4; ++cf) {
        const int col = col0 + 64*wc + 16*cf + ll;
        const float bv = fcb[col];
#pragma unroll
        for (int rf = 0; rf < 2; ++rf) {
#pragma unroll
            for (int r = 0; r < 4; ++r) {
                const int row = row0 + 32*wr + 16*rf + lg*4 + r;
                const float raw = accM[rf][cf][r] + accC[rf][cf][r] * INV_SCALE + bv;
                logits[((size_t)row * M_ + t) * V_ + col] = fin[rf][r] ? 0.0f : raw;
                if (raw > bvv[rf][r]) { bvv[rf][r] = raw; bii[rf][r] = col; } // cf asc
            }
        }
    }

#pragma unroll
    for (int rf = 0; rf < 2; ++rf) {
#pragma unroll
        for (int r = 0; r < 4; ++r) {
            float v = bvv[rf][r]; int ix = bii[rf][r];
#pragma unroll
            for (int m = 1; m < 16; m <<= 1) {
                const float ov = __shfl_xor(v, m);
                const int   oi = __shfl_xor(ix, m);
                if (ov > v || (ov == v && oi < ix)) { v = ov; ix = oi; }
            }
            if (ll == 0) {
                const int lr = 32*wr + 16*rf + lg*4 + r;
                pmS[lr][wc] = v; piS[lr][wc] = ix;
            }
        }
    }
    __syncthreads();
    if (tid < 64) {
        float v = pmS[tid][0]; int ix = piS[tid][0];
        const float v2 = pmS[tid][1]; const int i2 = piS[tid][1];
        if (v2 > v || (v2 == v && i2 < ix)) { v = v2; ix = i2; }
        pmax[(size_t)(row0 + tid) * 256 + ct] = v;
        pidx[(size_t)(row0 + tid) * 256 + ct] = ix;
    }
}

// ---------------------------------------------------------------------------
// final: write decoded/mask for step M-1 from the last fc partials.
// ---------------------------------------------------------------------------
__global__ __launch_bounds__(256)
void final_k(const float* __restrict__ pmax, const int* __restrict__ pidx,
             const int* __restrict__ finishedBuf,
             float* decoded, float* masko)
{
    const int row0 = blockIdx.x * 64;
    const int tid = threadIdx.x;
    const int wv = tid >> 6, lane = tid & 63;
    const int q = (M_ - 1) & 1;     // state parity of step 31
    for (int rr = wv; rr < 64; rr += 4) {
        const int brow = row0 + rr;
        float v = -INFINITY; int ix = 0x7fffffff;
        for (int s = lane; s < 125; s += 64) {
            const float v2 = pmax[(size_t)brow * 256 + s];
            const int   i2 = pidx[(size_t)brow * 256 + s];
            if (v2 > v || (v2 == v && i2 < ix)) { v = v2; ix = i2; }
        }
#pragma unroll
        for (int m = 1; m < 64; m <<= 1) {
            const float ov = __shfl_xor(v, m);
            const int   oi = __shfl_xor(ix, m);
            if (ov > v || (ov == v && oi < ix)) { v = ov; ix = oi; }
        }
        if (lane == 0) {
            const int finOld = finishedBuf[q * 256 + brow];
            decoded[brow * M_ + (M_ - 1)] = finOld ? -1.0f : (float)ix;
            masko  [brow * M_ + (M_ - 1)] = finOld ? 0.0f : 1.0f;
        }
    }
}

// ---------------------------------------------------------------------------
extern "C" void kernel_launch(void* const* d_in, const int* in_sizes, int n_in,
                              void* d_out, int out_size, void* d_ws, size_t ws_size,
                              hipStream_t stream)
{
    const float* sem_f = (const float*)d_in[0];
    const float* emb   = (const float*)d_in[1];
    const float* W_ih0 = (const float*)d_in[2];
    const float* W_hh0 = (const float*)d_in[3];
    const float* b_ih0 = (const float*)d_in[4];
    const float* b_hh0 = (const float*)d_in[5];
    const float* W_ih1 = (const float*)d_in[6];
    const float* W_hh1 = (const float*)d_in[7];
    const float* b_ih1 = (const float*)d_in[8];
    const float* b_hh1 = (const float*)d_in[9];
    const float* fc_W  = (const float*)d_in[10];
    const float* fc_b  = (const float*)d_in[11];

    float* out = (float*)d_out;
    float* decoded = out;
    float* logits  = out + (size_t)B_ * M_;
    float* masko   = out + (size_t)B_ * M_ + (size_t)B_ * M_ * V_;

    float* ws = (float*)d_ws;
    float*  PRE0 = ws;                            // 786432
    float*  PRE1 = ws + 786432;                   // 786432
    float*  h0f  = ws + 1572864;                  // 2 x 131072 (parity planes)
    float*  h1f  = ws + 1835008;                  // 131072
    half_t* h0a  = (half_t*)(ws + 1966080);       // 65536 f each
    half_t* h0b  = (half_t*)(ws + 2031616);
    half_t* h1a  = (half_t*)(ws + 2097152);
    half_t* h1b  = (half_t*)(ws + 2162688);
    half_t* xa   = (half_t*)(ws + 2228224);
    half_t* xb   = (half_t*)(ws + 2293760);
    float*  pmax = ws + 2359296;                  // 256*256
    int*    pidx = (int*)(ws + 2424832);          // 256*256
    int*    inputsBuf   = (int*)(ws + 2490368);   // 2 x 256
    int*    finishedBuf = (int*)(ws + 2490880);   // 2 x 256
    half_t* wi0a = (half_t*)(ws + 2491392);       // each GRU plane 393216 f
    half_t* wi0b = (half_t*)(ws + 2884608);
    half_t* wh0a = (half_t*)(ws + 3277824);
    half_t* wh0b = (half_t*)(ws + 3671040);
    half_t* wi1a = (half_t*)(ws + 4064256);
    half_t* wi1b = (half_t*)(ws + 4457472);
    half_t* wh1a = (half_t*)(ws + 4850688);
    half_t* wh1b = (half_t*)(ws + 5243904);
    half_t* fca  = (half_t*)(ws + 5637120);       // 4096000 f each
    half_t* fcbp = (half_t*)(ws + 9733120);
    // total 13,829,120 floats = 55.3 MB

    const int nGru4 = (1536 * 512) / 4;
    const int nFc4  = (V_ * H_) / 4;
    split_weights_k<<<(nGru4 + 255) / 256, 256, 0, stream>>>(W_ih0, wi0a, wi0b, nGru4);
    split_weights_k<<<(nGru4 + 255) / 256, 256, 0, stream>>>(W_hh0, wh0a, wh0b, nGru4);
    split_weights_k<<<(nGru4 + 255) / 256, 256, 0, stream>>>(W_ih1, wi1a, wi1b, nGru4);
    split_weights_k<<<(nGru4 + 255) / 256, 256, 0, stream>>>(W_hh1, wh1a, wh1b, nGru4);
    split_weights_k<<<(nFc4 + 255) / 256, 256, 0, stream>>>(fc_W, fca, fcbp, nFc4);
    init2_k<<<(B_ * H_) / 256, 256, 0, stream>>>(sem_f, h0f, h1f, h0a, h0b, h1a, h1b);

    for (int t = 0; t < M_; ++t) {
        gru0_k<<<192, 256, 0, stream>>>(
            xa, xb, h0a, h0b, wi0a, wi0b, wh0a, wh0b, b_ih0, b_hh0, PRE0,
            emb, pmax, pidx, inputsBuf, finishedBuf, decoded, masko, t);
        gru1_k<<<192, 256, 0, stream>>>(
            h0a, h0b, h1a, h1b, wi1a, wi1b, wh1a, wh1b, b_ih1, b_hh1,
            PRE0, PRE1, h0f, finishedBuf, t);
        gate1_k<<<(B_ * H_) / 256, 256, 0, stream>>>(
            PRE1, h1f, h1a, h1b, finishedBuf, t);
        fc_gemm_mfma<<<dim3(125, 4), 256, 0, stream>>>(
            h1a, h1b, fca, fcbp, fc_b, finishedBuf, logits, pmax, pidx, t);
    }
    final_k<<<4, 256, 0, stream>>>(pmax, pidx, finishedBuf, decoded, masko);
}

// Round 13
// 2980.300 us; speedup vs baseline: 6.6362x; 2.6838x over previous
//
#include <hip/hip_runtime.h>
#include <math.h>

#define B_   256
#define H_   512
#define V_   16000
#define M_   32
#define SOS_ 1
#define EOS_ 2
#define INV_SCALE (1.0f/2048.0f)

typedef _Float16 half_t;
typedef _Float16 f16x8 __attribute__((ext_vector_type(8)));
typedef _Float16 f16x4 __attribute__((ext_vector_type(4)));
typedef float    f32x4 __attribute__((ext_vector_type(4)));

__device__ __forceinline__ void split_f32(float x, half_t& a, half_t& b) {
    a = (half_t)x;
    b = (half_t)((x - (float)a) * 2048.0f);
}

// ---------------------------------------------------------------------------
// one-time weight split: fp32 -> fp16 hi/lo planes
// ---------------------------------------------------------------------------
__global__ __launch_bounds__(256)
void split_weights_k(const float* __restrict__ src, half_t* __restrict__ hi,
                     half_t* __restrict__ lo, int n4)
{
    const int i = blockIdx.x * 256 + threadIdx.x;
    if (i >= n4) return;
    const float4 v = ((const float4*)src)[i];
    f16x4 a, b; half_t t0, t1;
    split_f32(v.x, t0, t1); a[0] = t0; b[0] = t1;
    split_f32(v.y, t0, t1); a[1] = t0; b[1] = t1;
    split_f32(v.z, t0, t1); a[2] = t0; b[2] = t1;
    split_f32(v.w, t0, t1); a[3] = t0; b[3] = t1;
    ((f16x4*)hi)[i] = a;
    ((f16x4*)lo)[i] = b;
}

// ---------------------------------------------------------------------------
// init: h0 = h1 = sem_f (+ splits); x = emb[SOS] split; inputs; finished
// ---------------------------------------------------------------------------
__global__ __launch_bounds__(256)
void init_kernel(const float* __restrict__ sem_f, const float* __restrict__ emb,
                 float* __restrict__ h0, float* __restrict__ h1,
                 half_t* __restrict__ h0a, half_t* __restrict__ h0b,
                 half_t* __restrict__ h1a, half_t* __restrict__ h1b,
                 half_t* __restrict__ xa,  half_t* __restrict__ xb,
                 int* __restrict__ inputs, int* __restrict__ finished)
{
    const int i = blockIdx.x * 256 + threadIdx.x;
    if (i < B_ * H_) {
        const float v = sem_f[i];
        h0[i] = v; h1[i] = v;
        half_t a, b; split_f32(v, a, b);
        h0a[i] = a; h0b[i] = b;
        h1a[i] = a; h1b[i] = b;
        const int j = i & (H_ - 1);
        const float xv = emb[SOS_ * H_ + j];
        half_t c, d; split_f32(xv, c, d);
        xa[i] = c; xb[i] = d;
    }
    if (i < B_) { inputs[i] = SOS_; finished[i] = 0; }
}

// ---------------------------------------------------------------------------
// GRU GEMM: barrier-free, direct-global A and B fragments (W L2-resident).
// grid 192: ct = b%48 (ct<24 -> ih part), rt = b/48 (64-row group).
// tile 64 rows x 64 cols; 4 waves 2x2; wave 32r x 32c (rf=2, cf=2).
// ---------------------------------------------------------------------------
__global__ __launch_bounds__(256, 2)
void gru_bf_k(const half_t* __restrict__ Aia, const half_t* __restrict__ Aib,
              const half_t* __restrict__ Aha, const half_t* __restrict__ Ahb,
              const half_t* __restrict__ Wia, const half_t* __restrict__ Wib,
              const half_t* __restrict__ Wha, const half_t* __restrict__ Whb,
              const float* __restrict__ b_ih, const float* __restrict__ b_hh,
              float* __restrict__ PRE)
{
    const int bidx = blockIdx.x;
    const int ct = bidx % 48;
    const int rt = bidx / 48;            // 0..3
    const bool is_ih = (ct < 24);
    const int wrow0 = (is_ih ? ct : ct - 24) * 64;
    const int row0  = rt * 64;
    const float*  bias = is_ih ? b_ih : b_hh;
    const half_t* Aa = is_ih ? Aia : Aha;
    const half_t* Ab = is_ih ? Aib : Ahb;
    const half_t* W0 = is_ih ? Wia : Wha;
    const half_t* W1 = is_ih ? Wib : Whb;

    const int tid  = threadIdx.x;
    const int wv   = tid >> 6;
    const int wr   = wv >> 1, wc = wv & 1;
    const int lane = tid & 63;
    const int ll   = lane & 15, lg = lane >> 4;

    f32x4 accM[2][2] = {};
    f32x4 accC[2][2] = {};

    const size_t aoff0 = ((size_t)(row0 + 32*wr + ll) << 9) + (lg << 3);
    const size_t boff0 = ((size_t)(wrow0 + 32*wc + ll) << 9) + (lg << 3);

#pragma unroll 2
    for (int k0 = 0; k0 < H_; k0 += 32) {
        f16x8 a0[2], a1[2], b0[2], b1[2];
        a0[0] = *(const f16x8*)(Aa + aoff0 + k0);
        a0[1] = *(const f16x8*)(Aa + aoff0 + 8192 + k0);   // +16 rows * 512
        a1[0] = *(const f16x8*)(Ab + aoff0 + k0);
        a1[1] = *(const f16x8*)(Ab + aoff0 + 8192 + k0);
        b0[0] = *(const f16x8*)(W0 + boff0 + k0);
        b0[1] = *(const f16x8*)(W0 + boff0 + 8192 + k0);   // +16 cols * 512
        b1[0] = *(const f16x8*)(W1 + boff0 + k0);
        b1[1] = *(const f16x8*)(W1 + boff0 + 8192 + k0);
#pragma unroll
        for (int cf = 0; cf < 2; ++cf)
#pragma unroll
            for (int rf = 0; rf < 2; ++rf) {
                accM[rf][cf] = __builtin_amdgcn_mfma_f32_16x16x32_f16(a0[rf], b0[cf], accM[rf][cf], 0,0,0);
                accC[rf][cf] = __builtin_amdgcn_mfma_f32_16x16x32_f16(a0[rf], b1[cf], accC[rf][cf], 0,0,0);
                accC[rf][cf] = __builtin_amdgcn_mfma_f32_16x16x32_f16(a1[rf], b0[cf], accC[rf][cf], 0,0,0);
            }
    }

#pragma unroll
    for (int cf = 0; cf < 2; ++cf) {
        const int cl = 32*wc + 16*cf + ll;          // 0..63
        const float bv = bias[wrow0 + cl];
        const int c = ct * 64 + cl;                 // 0..3071
#pragma unroll
        for (int rf = 0; rf < 2; ++rf)
#pragma unroll
            for (int r = 0; r < 4; ++r) {
                const int row = row0 + 32*wr + 16*rf + lg*4 + r;
                PRE[(size_t)row * 3072 + c] = accM[rf][cf][r] + accC[rf][cf][r] * INV_SCALE + bv;
            }
    }
}

// ---------------------------------------------------------------------------
// GRU gate math; in-place h update with freeze + fp16x2 split emit.
// ---------------------------------------------------------------------------
__global__ __launch_bounds__(256)
void gate_kernel(const float* __restrict__ PRE,
                 float* __restrict__ h,
                 half_t* __restrict__ ha, half_t* __restrict__ hb,
                 const int* __restrict__ finished)
{
    const int idx = blockIdx.x * 256 + threadIdx.x;
    const int b = idx >> 9;
    const int j = idx & 511;
    if (finished[b]) return;
    const float* p = PRE + (size_t)b * 3072;
    const float ir = p[j],        iz = p[512 + j],  in_ = p[1024 + j];
    const float hr = p[1536 + j], hz = p[2048 + j], hn  = p[2560 + j];
    const float r = 1.0f / (1.0f + expf(-(ir + hr)));
    const float z = 1.0f / (1.0f + expf(-(iz + hz)));
    const float n = tanhf(in_ + r * hn);
    const float hv = (1.0f - z) * n + z * h[idx];
    h[idx] = hv;
    half_t a, bb; split_f32(hv, a, bb);
    ha[idx] = a; hb[idx] = bb;
}

// ---------------------------------------------------------------------------
// FC GEMM (round-3 body, proven): 128-col x 64-row tiles, grid (125,4).
// Waves 2x2; wave = 32 rows x 64 cols (rf=2, cf=4). LDS-staged W, 2 barriers.
// Epilogue: bias, logits store, argmax partials.
// ---------------------------------------------------------------------------
__global__ __launch_bounds__(256)
void fc_gemm_mfma(const half_t* __restrict__ Aa, const half_t* __restrict__ Ab,
                  const half_t* __restrict__ W0, const half_t* __restrict__ W1,
                  const float* __restrict__ fcb,
                  const int* __restrict__ finished,
                  float* __restrict__ logits,
                  float* __restrict__ pmax, int* __restrict__ pidx, int t)
{
    const int ct = blockIdx.x;            // 0..124
    const int rt = blockIdx.y;            // 0..3
    const int col0 = ct * 128;
    const int row0 = rt * 64;

    __shared__ half_t W0s[128][40];
    __shared__ half_t W1s[128][40];
    __shared__ float  pmS[64][2];
    __shared__ int    piS[64][2];

    const int tid  = threadIdx.x;
    const int wv   = tid >> 6;
    const int wr   = wv >> 1, wc = wv & 1;
    const int lane = tid & 63;
    const int ll   = lane & 15, lg = lane >> 4;

    const int sc = tid >> 1;
    const int sk = (tid & 1) * 16;
    const half_t* wp0 = W0 + (size_t)(col0 + sc) * H_ + sk;
    const half_t* wp1 = W1 + (size_t)(col0 + sc) * H_ + sk;

    f32x4 accM[2][4] = {};
    f32x4 accC[2][4] = {};

    for (int k0 = 0; k0 < H_; k0 += 32) {
        const f16x8 s0 = *(const f16x8*)(wp0 + k0);
        const f16x8 s1 = *(const f16x8*)(wp0 + k0 + 8);
        const f16x8 s2 = *(const f16x8*)(wp1 + k0);
        const f16x8 s3 = *(const f16x8*)(wp1 + k0 + 8);
        __syncthreads();
        *(f16x8*)&W0s[sc][sk]     = s0;
        *(f16x8*)&W0s[sc][sk + 8] = s1;
        *(f16x8*)&W1s[sc][sk]     = s2;
        *(f16x8*)&W1s[sc][sk + 8] = s3;
        __syncthreads();

        f16x8 a0[2], a1[2];
#pragma unroll
        for (int rf = 0; rf < 2; ++rf) {
            const size_t off = ((size_t)(row0 + 32*wr + 16*rf + ll) << 9) + k0 + (lg << 3);
            a0[rf] = *(const f16x8*)(Aa + off);
            a1[rf] = *(const f16x8*)(Ab + off);
        }
#pragma unroll
        for (int cf = 0; cf < 4; ++cf) {
            const int c = 64*wc + 16*cf + ll;
            const f16x8 b0 = *(const f16x8*)&W0s[c][lg << 3];
            const f16x8 b1 = *(const f16x8*)&W1s[c][lg << 3];
#pragma unroll
            for (int rf = 0; rf < 2; ++rf) {
                accM[rf][cf] = __builtin_amdgcn_mfma_f32_16x16x32_f16(a0[rf], b0, accM[rf][cf], 0,0,0);
                accC[rf][cf] = __builtin_amdgcn_mfma_f32_16x16x32_f16(a0[rf], b1, accC[rf][cf], 0,0,0);
                accC[rf][cf] = __builtin_amdgcn_mfma_f32_16x16x32_f16(a1[rf], b0, accC[rf][cf], 0,0,0);
            }
        }
    }

    int fin[2][4];
#pragma unroll
    for (int rf = 0; rf < 2; ++rf)
#pragma unroll
        for (int r = 0; r < 4; ++r)
            fin[rf][r] = finished[row0 + 32*wr + 16*rf + lg*4 + r];

    float bvv[2][4];
    int   bii[2][4];
#pragma unroll
    for (int rf = 0; rf < 2; ++rf)
#pragma unroll
        for (int r = 0; r < 4; ++r) { bvv[rf][r] = -INFINITY; bii[rf][r] = 0x7fffffff; }

#pragma unroll
    for (int cf = 0; cf < 4; ++cf) {
        const int col = col0 + 64*wc + 16*cf + ll;
        const float bv = fcb[col];
#pragma unroll
        for (int rf = 0; rf < 2; ++rf) {
#pragma unroll
            for (int r = 0; r < 4; ++r) {
                const int row = row0 + 32*wr + 16*rf + lg*4 + r;
                const float raw = accM[rf][cf][r] + accC[rf][cf][r] * INV_SCALE + bv;
                logits[((size_t)row * M_ + t) * V_ + col] = fin[rf][r] ? 0.0f : raw;
                if (raw > bvv[rf][r]) { bvv[rf][r] = raw; bii[rf][r] = col; } // cf asc
            }
        }
    }

#pragma unroll
    for (int rf = 0; rf < 2; ++rf) {
#pragma unroll
        for (int r = 0; r < 4; ++r) {
            float v = bvv[rf][r]; int ix = bii[rf][r];
#pragma unroll
            for (int m = 1; m < 16; m <<= 1) {
                const float ov = __shfl_xor(v, m);
                const int   oi = __shfl_xor(ix, m);
                if (ov > v || (ov == v && oi < ix)) { v = ov; ix = oi; }
            }
            if (ll == 0) {
                const int lr = 32*wr + 16*rf + lg*4 + r;
                pmS[lr][wc] = v; piS[lr][wc] = ix;
            }
        }
    }
    __syncthreads();
    if (tid < 64) {
        float v = pmS[tid][0]; int ix = piS[tid][0];
        const float v2 = pmS[tid][1]; const int i2 = piS[tid][1];
        if (v2 > v || (v2 == v && i2 < ix)) { v = v2; ix = i2; }
        pmax[(row0 + tid) * 128 + ct] = v;
        pidx[(row0 + tid) * 128 + ct] = ix;
    }
}

// ---------------------------------------------------------------------------
// finalize: reduce 125 partials per row, write decoded/mask, update state,
// gather+split next x.
// ---------------------------------------------------------------------------
__global__ __launch_bounds__(128)
void finalize_kernel(const float* __restrict__ pmax, const int* __restrict__ pidx,
                     const float* __restrict__ emb,
                     int* __restrict__ inputs, int* __restrict__ finished,
                     float* __restrict__ decoded_out, float* __restrict__ mask_out,
                     half_t* __restrict__ xa, half_t* __restrict__ xb, int t)
{
    const int b = blockIdx.x;
    const int tid = threadIdx.x;
    __shared__ float sv[128];
    __shared__ int   si[128];
    float v = -INFINITY; int ix = 0x7fffffff;
    if (tid < 125) { v = pmax[b * 128 + tid]; ix = pidx[b * 128 + tid]; }
    sv[tid] = v; si[tid] = ix;
    __syncthreads();
    for (int s = 64; s > 0; s >>= 1) {
        if (tid < s) {
            const float v2 = sv[tid + s]; const int i2 = si[tid + s];
            if (v2 > sv[tid] || (v2 == sv[tid] && i2 < si[tid])) { sv[tid] = v2; si[tid] = i2; }
        }
        __syncthreads();
    }
    __shared__ int s_tok;
    if (tid == 0) {
        const int fin = finished[b];
        const int dec = si[0];
        decoded_out[b * M_ + t] = fin ? -1.0f : (float)dec;
        mask_out   [b * M_ + t] = fin ? 0.0f : 1.0f;
        int tok;
        if (!fin) { inputs[b] = dec; if (dec == EOS_) finished[b] = 1; tok = dec; }
        else tok = inputs[b];
        s_tok = tok;
    }
    __syncthreads();
    const int tok = s_tok;
    for (int j = tid; j < H_; j += 128) {
        const float v2 = emb[(size_t)tok * H_ + j];
        half_t a, bb; split_f32(v2, a, bb);
        xa[b * H_ + j] = a; xb[b * H_ + j] = bb;
    }
}

// ---------------------------------------------------------------------------
extern "C" void kernel_launch(void* const* d_in, const int* in_sizes, int n_in,
                              void* d_out, int out_size, void* d_ws, size_t ws_size,
                              hipStream_t stream)
{
    const float* sem_f = (const float*)d_in[0];
    const float* emb   = (const float*)d_in[1];
    const float* W_ih0 = (const float*)d_in[2];
    const float* W_hh0 = (const float*)d_in[3];
    const float* b_ih0 = (const float*)d_in[4];
    const float* b_hh0 = (const float*)d_in[5];
    const float* W_ih1 = (const float*)d_in[6];
    const float* W_hh1 = (const float*)d_in[7];
    const float* b_ih1 = (const float*)d_in[8];
    const float* b_hh1 = (const float*)d_in[9];
    const float* fc_W  = (const float*)d_in[10];
    const float* fc_b  = (const float*)d_in[11];

    float* out = (float*)d_out;
    float* decoded_out = out;
    float* logits_out  = out + (size_t)B_ * M_;
    float* mask_out    = out + (size_t)B_ * M_ + (size_t)B_ * M_ * V_;

    // workspace carve (float units) — round-3 layout
    float*  ws  = (float*)d_ws;
    float*  PRE = ws;                                // 786432
    float*  h0  = ws + 786432;                       // 131072
    float*  h1  = ws + 917504;                       // 131072
    half_t* h0a = (half_t*)(ws + 1048576);           // 131072 h (65536 f) each
    half_t* h0b = (half_t*)(ws + 1114112);
    half_t* h1a = (half_t*)(ws + 1179648);
    half_t* h1b = (half_t*)(ws + 1245184);
    half_t* xa  = (half_t*)(ws + 1310720);
    half_t* xb  = (half_t*)(ws + 1376256);
    float*  pmax = ws + 1441792;                     // 256*128
    int*    pidx = (int*)(ws + 1474560);             // 256*128
    int*    inputs   = (int*)(ws + 1507328);
    int*    finished = (int*)(ws + 1507584);
    half_t* wi0a = (half_t*)(ws + 1507840);          // each 1536*512 h = 393216 f
    half_t* wi0b = (half_t*)(ws + 1901056);
    half_t* wh0a = (half_t*)(ws + 2294272);
    half_t* wh0b = (half_t*)(ws + 2687488);
    half_t* wi1a = (half_t*)(ws + 3080704);
    half_t* wi1b = (half_t*)(ws + 3473920);
    half_t* wh1a = (half_t*)(ws + 3867136);
    half_t* wh1b = (half_t*)(ws + 4260352);
    half_t* fca  = (half_t*)(ws + 4653568);          // 16000*512 h = 4096000 f
    half_t* fcbp = (half_t*)(ws + 8749568);          // low plane
    // total: 12,845,568 floats = 51.4 MB

    const int nGru4 = (1536 * 512) / 4;
    const int nFc4  = (V_ * H_) / 4;
    split_weights_k<<<(nGru4 + 255) / 256, 256, 0, stream>>>(W_ih0, wi0a, wi0b, nGru4);
    split_weights_k<<<(nGru4 + 255) / 256, 256, 0, stream>>>(W_hh0, wh0a, wh0b, nGru4);
    split_weights_k<<<(nGru4 + 255) / 256, 256, 0, stream>>>(W_ih1, wi1a, wi1b, nGru4);
    split_weights_k<<<(nGru4 + 255) / 256, 256, 0, stream>>>(W_hh1, wh1a, wh1b, nGru4);
    split_weights_k<<<(nFc4 + 255) / 256, 256, 0, stream>>>(fc_W, fca, fcbp, nFc4);

    init_kernel<<<(B_ * H_ + 255) / 256, 256, 0, stream>>>(
        sem_f, emb, h0, h1, h0a, h0b, h1a, h1b, xa, xb, inputs, finished);

    const dim3 fcGrid(125, 4);

    for (int t = 0; t < M_; ++t) {
        gru_bf_k<<<192, 256, 0, stream>>>(
            xa, xb, h0a, h0b, wi0a, wi0b, wh0a, wh0b, b_ih0, b_hh0, PRE);
        gate_kernel<<<(B_ * H_) / 256, 256, 0, stream>>>(PRE, h0, h0a, h0b, finished);
        gru_bf_k<<<192, 256, 0, stream>>>(
            h0a, h0b, h1a, h1b, wi1a, wi1b, wh1a, wh1b, b_ih1, b_hh1, PRE);
        gate_kernel<<<(B_ * H_) / 256, 256, 0, stream>>>(PRE, h1, h1a, h1b, finished);
        fc_gemm_mfma<<<fcGrid, 256, 0, stream>>>(
            h1a, h1b, fca, fcbp, fc_b, finished, logits_out, pmax, pidx, t);
        finalize_kernel<<<B_, 128, 0, stream>>>(
            pmax, pidx, emb, inputs, finished, decoded_out, mask_out, xa, xb, t);
    }
}